// Round 1
// baseline (264.486 us; speedup 1.0000x reference)
//
#include <hip/hip_runtime.h>

// NT-Xent loss, B=4096, D=256, N=16384, T=0.5.
// loss = mean_i( -pos_i + log(sum_{j!=i} exp(2*dot(zn_i, zn_j)) + 1e-12) )
//
// ws layout:
//   [0, 8MB)            : zb   — l2-normalized z, bf16, [16384][256]
//   [8MB, 16MB)         : part — per-colblock row sums, f32, [128][16384] (part[bcol][row])
//   [16MB, 16MB+16KB)   : pospart[4096]
//   [16MB+16KB, +256B)  : logpart[64]
// Every ws slot is fully rewritten each launch -> no memset needed (0xAA poison safe).

typedef __bf16 bf16;
typedef __bf16 bf16x4 __attribute__((ext_vector_type(4)));
typedef __bf16 bf16x8 __attribute__((ext_vector_type(8)));
typedef float  f32x4  __attribute__((ext_vector_type(4)));

#define NTOT 16384
#define DDIM 256

__device__ __forceinline__ float dot4(float4 a, float4 b) {
    return a.x * b.x + a.y * b.y + a.z * b.z + a.w * b.w;
}

// ---------------- kernel 1: normalize rows -> bf16 ----------------
__global__ __launch_bounds__(256) void normk(const float* __restrict__ z1,
                                             const float* __restrict__ z2,
                                             const float* __restrict__ z3,
                                             const float* __restrict__ z4,
                                             bf16* __restrict__ zb) {
    const int wave = threadIdx.x >> 6;
    const int lane = threadIdx.x & 63;
    const int r    = blockIdx.x * 4 + wave;           // 0..16383
    const float* src = (r < 4096) ? z1 : (r < 8192) ? z2 : (r < 12288) ? z3 : z4;
    const float4* p = (const float4*)(src + (size_t)(r & 4095) * DDIM);
    float4 v = p[lane];
    float s = dot4(v, v);
#pragma unroll
    for (int m = 32; m >= 1; m >>= 1) s += __shfl_xor(s, m, 64);
    const float sc = 1.0f / fmaxf(sqrtf(s), 1e-12f);
    bf16x4 o;
    o.x = (bf16)(v.x * sc);
    o.y = (bf16)(v.y * sc);
    o.z = (bf16)(v.z * sc);
    o.w = (bf16)(v.w * sc);
    *(bf16x4*)(zb + (size_t)r * DDIM + lane * 4) = o;
}

// ---------------- kernel 2: fused Gram-matrix exp-rowsum ----------------
// 128x128 tile per block; 4 waves in 2x2 of 64x64; mfma_f32_16x16x32_bf16.
// LDS granule-xor swizzle: granule g of row r stored at slot (g ^ (r&7)).
__global__ __launch_bounds__(256, 3) void tilek(const bf16* __restrict__ zb,
                                                float* __restrict__ part) {
    __shared__ __attribute__((aligned(16))) char lds[32768]; // A:[0,16K) B:[16K,32K)
    __shared__ float rsum_lds[2][128];

    const int tid  = threadIdx.x;
    const int wave = tid >> 6;
    const int lane = tid & 63;

    // XCD-aware super-tile swizzle: 8x8 supertiles of 16x16 blocks.
    int bid    = blockIdx.x;
    int xcd    = bid & 7;
    int j      = bid >> 3;
    int super  = ((j >> 8) << 3) + xcd;   // 0..63
    int within = j & 255;
    int brow   = ((super >> 3) << 4) + (within >> 4);  // 0..127
    int bcol   = ((super & 7) << 4) + (within & 15);   // 0..127

    const char* gA = (const char*)zb + (size_t)brow * 128 * 512; // row stride 512B
    const char* gB = (const char*)zb + (size_t)bcol * 128 * 512;

    const int quad = lane >> 4;
    const int l15  = lane & 15;
    const int wr   = wave >> 1, wc = wave & 1;

    f32x4 zero = {0.f, 0.f, 0.f, 0.f};
    f32x4 acc[4][4];
#pragma unroll
    for (int a = 0; a < 4; ++a)
#pragma unroll
        for (int b = 0; b < 4; ++b) acc[a][b] = zero;

    const int strow = lane >> 3;  // row within 8-row group
    const int sslot = lane & 7;   // swizzled granule slot this lane fills

    for (int ko = 0; ko < 4; ++ko) {
        // stage A and B 128x64 slices (16KB each); 4+4 1KB wave-loads per wave
#pragma unroll
        for (int s4 = 0; s4 < 4; ++s4) {
            int t   = (wave << 2) + s4;        // 0..15
            int row = (t << 3) + strow;        // 0..127
            int g   = sslot ^ (row & 7);       // global granule to fetch
            size_t goff = (size_t)row * 512 + ko * 128 + g * 16;
            __builtin_amdgcn_global_load_lds(
                (const __attribute__((address_space(1))) unsigned int*)(gA + goff),
                (__attribute__((address_space(3))) unsigned int*)(lds + t * 1024),
                16, 0, 0);
            __builtin_amdgcn_global_load_lds(
                (const __attribute__((address_space(1))) unsigned int*)(gB + goff),
                (__attribute__((address_space(3))) unsigned int*)(lds + 16384 + t * 1024),
                16, 0, 0);
        }
        __syncthreads();
#pragma unroll
        for (int ks = 0; ks < 2; ++ks) {
            bf16x8 af[4], bfr[4];
            const int gg = (ks << 2) + quad;   // granule within 64-col slice
#pragma unroll
            for (int rt = 0; rt < 4; ++rt) {
                int arow = (wr << 6) + (rt << 4) + l15;
                int addr = arow * 128 + ((gg ^ (arow & 7)) << 4);
                af[rt] = *(const bf16x8*)(lds + addr);
            }
#pragma unroll
            for (int ct = 0; ct < 4; ++ct) {
                int brw  = (wc << 6) + (ct << 4) + l15;
                int addr = 16384 + brw * 128 + ((gg ^ (brw & 7)) << 4);
                bfr[ct] = *(const bf16x8*)(lds + addr);
            }
#pragma unroll
            for (int rt = 0; rt < 4; ++rt)
#pragma unroll
                for (int ct = 0; ct < 4; ++ct)
                    acc[rt][ct] = __builtin_amdgcn_mfma_f32_16x16x32_bf16(
                        af[rt], bfr[ct], acc[rt][ct], 0, 0, 0);
        }
        __syncthreads();
    }

    // epilogue: exp(2*acc), mask diagonal, reduce over columns
    const int rb = wr << 6;
    const int cb = wc << 6;
#pragma unroll
    for (int rt = 0; rt < 4; ++rt) {
        float rs[4] = {0.f, 0.f, 0.f, 0.f};
        const int growt = brow * 128 + rb + (rt << 4); // tile row base (global)
#pragma unroll
        for (int ct = 0; ct < 4; ++ct) {
            const int gcolt = bcol * 128 + cb + (ct << 4);
            const bool diag = (growt == gcolt);
#pragma unroll
            for (int r = 0; r < 4; ++r) {
                float e = __expf(2.0f * acc[rt][ct][r]);
                if (diag && ((quad << 2) + r) == l15) e = 0.f; // self-sim
                rs[r] += e;
            }
        }
        // sum across 16 lanes (C-layout: col = lane&15)
#pragma unroll
        for (int m = 1; m <= 8; m <<= 1)
#pragma unroll
            for (int r = 0; r < 4; ++r) rs[r] += __shfl_xor(rs[r], m, 64);
        if (l15 == 0) {
            int lrow = rb + (rt << 4) + (quad << 2);
#pragma unroll
            for (int r = 0; r < 4; ++r) rsum_lds[wc][lrow + r] = rs[r];
        }
    }
    __syncthreads();
    if (tid < 128) {
        float v = rsum_lds[0][tid] + rsum_lds[1][tid];
        part[(size_t)bcol * NTOT + brow * 128 + tid] = v;
    }
}

// ---------------- kernel 3: positive-pair similarities (fp32 exact) ----------------
__global__ __launch_bounds__(256) void posk(const float* __restrict__ z1,
                                            const float* __restrict__ z2,
                                            const float* __restrict__ z3,
                                            const float* __restrict__ z4,
                                            float* __restrict__ pospart) {
    const int wave = threadIdx.x >> 6;
    const int lane = threadIdx.x & 63;
    const int i    = blockIdx.x * 4 + wave; // 0..4095
    const float4* p1 = (const float4*)(z1 + (size_t)i * DDIM);
    const float4* p2 = (const float4*)(z2 + (size_t)i * DDIM);
    const float4* p3 = (const float4*)(z3 + (size_t)i * DDIM);
    const float4* p4 = (const float4*)(z4 + (size_t)i * DDIM);
    float4 a = p1[lane], b = p2[lane], c = p3[lane], d = p4[lane];
    float s11 = dot4(a, a), s22 = dot4(b, b), s33 = dot4(c, c), s44 = dot4(d, d);
    float s12 = dot4(a, b), s23 = dot4(b, c), s34 = dot4(c, d), s41 = dot4(d, a);
#pragma unroll
    for (int m = 32; m >= 1; m >>= 1) {
        s11 += __shfl_xor(s11, m, 64); s22 += __shfl_xor(s22, m, 64);
        s33 += __shfl_xor(s33, m, 64); s44 += __shfl_xor(s44, m, 64);
        s12 += __shfl_xor(s12, m, 64); s23 += __shfl_xor(s23, m, 64);
        s34 += __shfl_xor(s34, m, 64); s41 += __shfl_xor(s41, m, 64);
    }
    if (lane == 0) {
        float m1 = fmaxf(sqrtf(s11), 1e-12f), m2 = fmaxf(sqrtf(s22), 1e-12f);
        float m3 = fmaxf(sqrtf(s33), 1e-12f), m4 = fmaxf(sqrtf(s44), 1e-12f);
        pospart[i] = 2.0f * (s12 / (m1 * m2) + s23 / (m2 * m3) +
                             s34 / (m3 * m4) + s41 / (m4 * m1));
    }
}

// ---------------- kernel 4: reduce partials per row, take log ----------------
__global__ __launch_bounds__(256) void rowlog(const float* __restrict__ part,
                                              float* __restrict__ logpart) {
    const int row = blockIdx.x * 256 + threadIdx.x;
    float s = 0.f;
    for (int c = 0; c < 128; ++c) s += part[(size_t)c * NTOT + row];
    float lg = logf(s + 1e-12f);
#pragma unroll
    for (int m = 32; m >= 1; m >>= 1) lg += __shfl_xor(lg, m, 64);
    __shared__ float red[4];
    const int wave = threadIdx.x >> 6, lane = threadIdx.x & 63;
    if (lane == 0) red[wave] = lg;
    __syncthreads();
    if (threadIdx.x == 0) logpart[blockIdx.x] = red[0] + red[1] + red[2] + red[3];
}

// ---------------- kernel 5: finalize ----------------
__global__ __launch_bounds__(256) void finalk(const float* __restrict__ pospart,
                                              const float* __restrict__ logpart,
                                              float* __restrict__ out) {
    const int t = threadIdx.x;
    float sp = 0.f, sl = 0.f;
    for (int k = t; k < 4096; k += 256) sp += pospart[k];
    if (t < 64) sl = logpart[t];
#pragma unroll
    for (int m = 32; m >= 1; m >>= 1) { sp += __shfl_xor(sp, m, 64); sl += __shfl_xor(sl, m, 64); }
    __shared__ float rp[4], rl[4];
    const int wave = t >> 6, lane = t & 63;
    if (lane == 0) { rp[wave] = sp; rl[wave] = sl; }
    __syncthreads();
    if (t == 0) {
        float P = rp[0] + rp[1] + rp[2] + rp[3];
        float L = rl[0] + rl[1] + rl[2] + rl[3];
        out[0] = (L - P) / 16384.0f;
    }
}

extern "C" void kernel_launch(void* const* d_in, const int* in_sizes, int n_in,
                              void* d_out, int out_size, void* d_ws, size_t ws_size,
                              hipStream_t stream) {
    const float* z1 = (const float*)d_in[0];
    const float* z2 = (const float*)d_in[1];
    const float* z3 = (const float*)d_in[2];
    const float* z4 = (const float*)d_in[3];
    float* out = (float*)d_out;

    char* ws = (char*)d_ws;
    bf16*  zb      = (bf16*)ws;                                  // 8 MB
    float* part    = (float*)(ws + (size_t)(8u << 20));          // 8 MB
    float* pospart = (float*)(ws + (size_t)(16u << 20));         // 16 KB
    float* logpart = (float*)(ws + (size_t)(16u << 20) + 16384); // 256 B

    normk<<<4096, 256, 0, stream>>>(z1, z2, z3, z4, zb);
    posk<<<1024, 256, 0, stream>>>(z1, z2, z3, z4, pospart);
    tilek<<<16384, 256, 0, stream>>>(zb, part);
    rowlog<<<64, 256, 0, stream>>>(part, logpart);
    finalk<<<1, 256, 0, stream>>>(pospart, logpart, out);
}

// Round 2
// 171.231 us; speedup vs baseline: 1.5446x; 1.5446x over previous
//
#include <hip/hip_runtime.h>

// NT-Xent loss, B=4096, D=256, N=16384, T=0.5.
// loss = mean_i( -pos_i + log(sum_{j!=i} exp(2*dot(zn_i, zn_j)) + 1e-12) )
//
// R2: exploit Gram-matrix symmetry — compute only upper-triangle 128x128 tiles
// (8256 blocks vs 16384); off-diagonal blocks emit both row-sums and col-sums.
// Fuse normalize+pos into one kernel.
//
// ws layout:
//   [0, 8MB)            : zb   — l2-normalized z, bf16, [16384][256]
//   [8MB, 16MB)         : part — per-colblock row sums, f32, [128][16384] (part[cblk][row])
//   [16MB, 16MB+16KB)   : pospart[4096]
//   [16MB+16KB, +256B)  : logpart[64]
// Every ws slot is written exactly once per launch -> no memset needed.

typedef __bf16 bf16;
typedef __bf16 bf16x4 __attribute__((ext_vector_type(4)));
typedef __bf16 bf16x8 __attribute__((ext_vector_type(8)));
typedef float  f32x4  __attribute__((ext_vector_type(4)));

#define NTOT 16384
#define DDIM 256

__device__ __forceinline__ float dot4(float4 a, float4 b) {
    return a.x * b.x + a.y * b.y + a.z * b.z + a.w * b.w;
}

// ---------------- kernel 1: normalize rows -> bf16, plus positive-pair sims ----------------
__global__ __launch_bounds__(256) void norm4k(const float* __restrict__ z1,
                                              const float* __restrict__ z2,
                                              const float* __restrict__ z3,
                                              const float* __restrict__ z4,
                                              bf16* __restrict__ zb,
                                              float* __restrict__ pospart) {
    const int wave = threadIdx.x >> 6;
    const int lane = threadIdx.x & 63;
    const int i    = blockIdx.x * 4 + wave; // 0..4095
    const float4* p1 = (const float4*)(z1 + (size_t)i * DDIM);
    const float4* p2 = (const float4*)(z2 + (size_t)i * DDIM);
    const float4* p3 = (const float4*)(z3 + (size_t)i * DDIM);
    const float4* p4 = (const float4*)(z4 + (size_t)i * DDIM);
    float4 a = p1[lane], b = p2[lane], c = p3[lane], d = p4[lane];
    float s11 = dot4(a, a), s22 = dot4(b, b), s33 = dot4(c, c), s44 = dot4(d, d);
    float s12 = dot4(a, b), s23 = dot4(b, c), s34 = dot4(c, d), s41 = dot4(d, a);
#pragma unroll
    for (int m = 32; m >= 1; m >>= 1) {
        s11 += __shfl_xor(s11, m, 64); s22 += __shfl_xor(s22, m, 64);
        s33 += __shfl_xor(s33, m, 64); s44 += __shfl_xor(s44, m, 64);
        s12 += __shfl_xor(s12, m, 64); s23 += __shfl_xor(s23, m, 64);
        s34 += __shfl_xor(s34, m, 64); s41 += __shfl_xor(s41, m, 64);
    }
    const float m1 = fmaxf(sqrtf(s11), 1e-12f), m2 = fmaxf(sqrtf(s22), 1e-12f);
    const float m3 = fmaxf(sqrtf(s33), 1e-12f), m4 = fmaxf(sqrtf(s44), 1e-12f);
    const float i1 = 1.0f / m1, i2 = 1.0f / m2, i3 = 1.0f / m3, i4 = 1.0f / m4;
    bf16x4 o;
    o.x = (bf16)(a.x * i1); o.y = (bf16)(a.y * i1); o.z = (bf16)(a.z * i1); o.w = (bf16)(a.w * i1);
    *(bf16x4*)(zb + (size_t)i * DDIM + lane * 4) = o;
    o.x = (bf16)(b.x * i2); o.y = (bf16)(b.y * i2); o.z = (bf16)(b.z * i2); o.w = (bf16)(b.w * i2);
    *(bf16x4*)(zb + (size_t)(i + 4096) * DDIM + lane * 4) = o;
    o.x = (bf16)(c.x * i3); o.y = (bf16)(c.y * i3); o.z = (bf16)(c.z * i3); o.w = (bf16)(c.w * i3);
    *(bf16x4*)(zb + (size_t)(i + 8192) * DDIM + lane * 4) = o;
    o.x = (bf16)(d.x * i4); o.y = (bf16)(d.y * i4); o.z = (bf16)(d.z * i4); o.w = (bf16)(d.w * i4);
    *(bf16x4*)(zb + (size_t)(i + 12288) * DDIM + lane * 4) = o;
    if (lane == 0)
        pospart[i] = 2.0f * (s12 * i1 * i2 + s23 * i2 * i3 + s34 * i3 * i4 + s41 * i4 * i1);
}

// ---------------- kernel 2: fused Gram-matrix exp-rowsum, upper triangle ----------------
// 128x128 tile per block; 4 waves in 2x2 of 64x64; mfma_f32_16x16x32_bf16.
// LDS granule-xor swizzle: granule g of row r stored at slot (g ^ (r&7)).
__global__ __launch_bounds__(256, 4) void tilek(const bf16* __restrict__ zb,
                                                float* __restrict__ part) {
    __shared__ __attribute__((aligned(16))) char lds[32768]; // A:[0,16K) B:[16K,32K)
    __shared__ float rsum_lds[2][128];
    __shared__ float csum_lds[2][128];

    const int tid  = threadIdx.x;
    const int wave = tid >> 6;
    const int lane = tid & 63;

    // triangular decode: k -> (brow, bcol), brow <= bcol, 128x129/2 = 8256 tiles
    const int k = blockIdx.x;
    int brow = (int)((257.0 - sqrt(257.0 * 257.0 - 8.0 * (double)k)) * 0.5);
    if (brow > 127) brow = 127;
    // f(r) = r*128 - r*(r-1)/2 = tiles before row r
    while (brow < 127 && ((brow + 1) * 128 - ((brow + 1) * brow) / 2) <= k) ++brow;
    while (brow > 0 && (brow * 128 - (brow * (brow - 1)) / 2) > k) --brow;
    const int bcol = brow + (k - (brow * 128 - (brow * (brow - 1)) / 2));
    const bool isdiag = (brow == bcol);

    const char* gA = (const char*)zb + (size_t)brow * 128 * 512; // row stride 512B
    const char* gB = (const char*)zb + (size_t)bcol * 128 * 512;

    const int quad = lane >> 4;
    const int l15  = lane & 15;
    const int wr   = wave >> 1, wc = wave & 1;

    f32x4 zero = {0.f, 0.f, 0.f, 0.f};
    f32x4 acc[4][4];
#pragma unroll
    for (int a = 0; a < 4; ++a)
#pragma unroll
        for (int b = 0; b < 4; ++b) acc[a][b] = zero;

    const int strow = lane >> 3;  // row within 8-row group
    const int sslot = lane & 7;   // swizzled granule slot this lane fills

    for (int ko = 0; ko < 4; ++ko) {
        // stage A and B 128x64 slices (16KB each); 4+4 1KB wave-loads per wave
#pragma unroll
        for (int s4 = 0; s4 < 4; ++s4) {
            int t   = (wave << 2) + s4;        // 0..15
            int row = (t << 3) + strow;        // 0..127
            int g   = sslot ^ (row & 7);       // global granule to fetch
            size_t goff = (size_t)row * 512 + ko * 128 + g * 16;
            __builtin_amdgcn_global_load_lds(
                (const __attribute__((address_space(1))) unsigned int*)(gA + goff),
                (__attribute__((address_space(3))) unsigned int*)(lds + t * 1024),
                16, 0, 0);
            __builtin_amdgcn_global_load_lds(
                (const __attribute__((address_space(1))) unsigned int*)(gB + goff),
                (__attribute__((address_space(3))) unsigned int*)(lds + 16384 + t * 1024),
                16, 0, 0);
        }
        __syncthreads();
#pragma unroll
        for (int ks = 0; ks < 2; ++ks) {
            bf16x8 af[4], bfr[4];
            const int gg = (ks << 2) + quad;   // granule within 64-col slice
#pragma unroll
            for (int rt = 0; rt < 4; ++rt) {
                int arow = (wr << 6) + (rt << 4) + l15;
                int addr = arow * 128 + ((gg ^ (arow & 7)) << 4);
                af[rt] = *(const bf16x8*)(lds + addr);
            }
#pragma unroll
            for (int ct = 0; ct < 4; ++ct) {
                int brw  = (wc << 6) + (ct << 4) + l15;
                int addr = 16384 + brw * 128 + ((gg ^ (brw & 7)) << 4);
                bfr[ct] = *(const bf16x8*)(lds + addr);
            }
#pragma unroll
            for (int rt = 0; rt < 4; ++rt)
#pragma unroll
                for (int ct = 0; ct < 4; ++ct)
                    acc[rt][ct] = __builtin_amdgcn_mfma_f32_16x16x32_bf16(
                        af[rt], bfr[ct], acc[rt][ct], 0, 0, 0);
        }
        __syncthreads();
    }

    // epilogue: e = exp(2*acc) (diag masked); row-sums over lane&15, col-sums over quad.
    const int rb = wr << 6;
    const int cb = wc << 6;
    float cs[4] = {0.f, 0.f, 0.f, 0.f};
#pragma unroll
    for (int rt = 0; rt < 4; ++rt) {
        float rs[4] = {0.f, 0.f, 0.f, 0.f};
        const int rtile = rb + (rt << 4); // tile-local row base
#pragma unroll
        for (int ct = 0; ct < 4; ++ct) {
            const int ctile = cb + (ct << 4);
            const bool tdiag = isdiag && (rtile == ctile);
#pragma unroll
            for (int r = 0; r < 4; ++r) {
                float e = __expf(2.0f * acc[rt][ct][r]);
                if (tdiag && ((quad << 2) + r) == l15) e = 0.f; // self-sim
                rs[r] += e;
                cs[ct] += e;
            }
        }
        // row-sums: reduce across 16 lanes (C-layout: col = lane&15)
#pragma unroll
        for (int m = 1; m <= 8; m <<= 1)
#pragma unroll
            for (int r = 0; r < 4; ++r) rs[r] += __shfl_xor(rs[r], m, 64);
        if (l15 == 0) {
            int lrow = rb + (rt << 4) + (quad << 2);
#pragma unroll
            for (int r = 0; r < 4; ++r) rsum_lds[wc][lrow + r] = rs[r];
        }
    }
    // col-sums: reduce across the 4 quads (rows), lanes 16 apart
#pragma unroll
    for (int m = 16; m <= 32; m <<= 1)
#pragma unroll
        for (int ct = 0; ct < 4; ++ct) cs[ct] += __shfl_xor(cs[ct], m, 64);
    if (quad == 0) {
#pragma unroll
        for (int ct = 0; ct < 4; ++ct) csum_lds[wr][cb + (ct << 4) + l15] = cs[ct];
    }
    __syncthreads();
    if (tid < 128) {
        float rv = rsum_lds[0][tid] + rsum_lds[1][tid];
        part[(size_t)bcol * NTOT + brow * 128 + tid] = rv;
        if (!isdiag) {
            float cv = csum_lds[0][tid] + csum_lds[1][tid];
            part[(size_t)brow * NTOT + bcol * 128 + tid] = cv;
        }
    }
}

// ---------------- kernel 3: reduce partials per row, take log ----------------
__global__ __launch_bounds__(256) void rowlog(const float* __restrict__ part,
                                              float* __restrict__ logpart) {
    const int row = blockIdx.x * 256 + threadIdx.x;
    float s = 0.f;
    for (int c = 0; c < 128; ++c) s += part[(size_t)c * NTOT + row];
    float lg = logf(s + 1e-12f);
#pragma unroll
    for (int m = 32; m >= 1; m >>= 1) lg += __shfl_xor(lg, m, 64);
    __shared__ float red[4];
    const int wave = threadIdx.x >> 6, lane = threadIdx.x & 63;
    if (lane == 0) red[wave] = lg;
    __syncthreads();
    if (threadIdx.x == 0) logpart[blockIdx.x] = red[0] + red[1] + red[2] + red[3];
}

// ---------------- kernel 4: finalize ----------------
__global__ __launch_bounds__(256) void finalk(const float* __restrict__ pospart,
                                              const float* __restrict__ logpart,
                                              float* __restrict__ out) {
    const int t = threadIdx.x;
    float sp = 0.f, sl = 0.f;
    for (int k = t; k < 4096; k += 256) sp += pospart[k];
    if (t < 64) sl = logpart[t];
#pragma unroll
    for (int m = 32; m >= 1; m >>= 1) { sp += __shfl_xor(sp, m, 64); sl += __shfl_xor(sl, m, 64); }
    __shared__ float rp[4], rl[4];
    const int wave = t >> 6, lane = t & 63;
    if (lane == 0) { rp[wave] = sp; rl[wave] = sl; }
    __syncthreads();
    if (t == 0) {
        float P = rp[0] + rp[1] + rp[2] + rp[3];
        float L = rl[0] + rl[1] + rl[2] + rl[3];
        out[0] = (L - P) / 16384.0f;
    }
}

extern "C" void kernel_launch(void* const* d_in, const int* in_sizes, int n_in,
                              void* d_out, int out_size, void* d_ws, size_t ws_size,
                              hipStream_t stream) {
    const float* z1 = (const float*)d_in[0];
    const float* z2 = (const float*)d_in[1];
    const float* z3 = (const float*)d_in[2];
    const float* z4 = (const float*)d_in[3];
    float* out = (float*)d_out;

    char* ws = (char*)d_ws;
    bf16*  zb      = (bf16*)ws;                                  // 8 MB
    float* part    = (float*)(ws + (size_t)(8u << 20));          // 8 MB
    float* pospart = (float*)(ws + (size_t)(16u << 20));         // 16 KB
    float* logpart = (float*)(ws + (size_t)(16u << 20) + 16384); // 256 B

    norm4k<<<1024, 256, 0, stream>>>(z1, z2, z3, z4, zb, pospart);
    tilek<<<8256, 256, 0, stream>>>(zb, part);
    rowlog<<<64, 256, 0, stream>>>(part, logpart);
    finalk<<<1, 256, 0, stream>>>(pospart, logpart, out);
}